// Round 8
// baseline (1341.016 us; speedup 1.0000x reference)
//
#include <hip/hip_runtime.h>
#include <hip/hip_bf16.h>
#include <stdint.h>

// ---------------- problem constants ----------------
#define BATCH 2
#define SEQ   2048
#define DM    1024
#define DS    16
#define PROJ  34816          // 2*DM + 2*DM*DS
#define MTOK  4096           // BATCH*SEQ
#define KDIM  1024
#define NCHUNK 16
#define CHUNK  128           // SEQ / NCHUNK
#define NCH    32768         // BATCH*DM*DS scan channels

typedef unsigned short u16;
typedef unsigned int   u32;
typedef __attribute__((ext_vector_type(8))) __bf16 bf16x8;
typedef __attribute__((ext_vector_type(4))) float  f32x4;

// xp element load/store, overloaded on storage type (f32 primary, bf16 fallback)
__device__ __forceinline__ float ldf(const float* p) { return *p; }
__device__ __forceinline__ float ldf(const __hip_bfloat16* p) { return __bfloat162float(*p); }
__device__ __forceinline__ void stf(float* p, float v) { *p = v; }
__device__ __forceinline__ void stf(__hip_bfloat16* p, float v) { *p = __float2bfloat16(v); }

// async global->LDS, 16B per lane. LDS dest must be linear in lane (it is:
// per-thread lds ptr = base + tid*16B). Per-lane GLOBAL source is allowed —
// that's how the swizzled LDS layout is realized (inverse-swizzled source).
__device__ __forceinline__ void gl16(const void* g, void* l) {
  __builtin_amdgcn_global_load_lds(
      (const __attribute__((address_space(1))) u32*)g,
      (__attribute__((address_space(3))) u32*)(u32)(uintptr_t)l,
      16, 0, 0);
}

__device__ __forceinline__ f32x4 mfma16(bf16x8 a, bf16x8 b, f32x4 c) {
  return __builtin_amdgcn_mfma_f32_16x16x32_bf16(a, b, c, 0, 0, 0);
}

// ---------------- split f32 -> bf16 hi + bf16 lo ----------------
__global__ __launch_bounds__(256)
void split_kernel(const float* __restrict__ src, u16* __restrict__ hi,
                  u16* __restrict__ lo, int n4) {
  int i = blockIdx.x * 256 + threadIdx.x;
  if (i >= n4) return;
  float4 v = reinterpret_cast<const float4*>(src)[i];
  ushort4 h, l;
  {
    __hip_bfloat16 bh, bl;
    bh = __float2bfloat16(v.x); bl = __float2bfloat16(v.x - __bfloat162float(bh));
    h.x = *(u16*)&bh; l.x = *(u16*)&bl;
    bh = __float2bfloat16(v.y); bl = __float2bfloat16(v.y - __bfloat162float(bh));
    h.y = *(u16*)&bh; l.y = *(u16*)&bl;
    bh = __float2bfloat16(v.z); bl = __float2bfloat16(v.z - __bfloat162float(bh));
    h.z = *(u16*)&bh; l.z = *(u16*)&bl;
    bh = __float2bfloat16(v.w); bl = __float2bfloat16(v.w - __bfloat162float(bh));
    h.w = *(u16*)&bh; l.w = *(u16*)&bl;
  }
  reinterpret_cast<ushort4*>(hi)[i] = h;
  reinterpret_cast<ushort4*>(lo)[i] = l;
}

// ---------------- GEMM: xp = x @ W^T + b (3-product bf16 emulation) -------
// 256x256 tile, BK=32, 8 waves (2M x 4N), per-wave 128x64 output.
// LDS row layout: [row][hi 64B | lo 64B] = 128B rows, XOR-swizzled
// (byte ^= (row&7)<<4) -> conflict-free ds_read_b128. Staged via
// global_load_lds with inverse-swizzled per-lane source addresses.
// Double-buffered; raw s_barrier with FULL drain (vmcnt AND lgkmcnt — the
// lgkmcnt drain is required: without it a sunk MFMA can leave ds_reads
// outstanding across the barrier while the next stage overwrites the
// buffer). Stage for tile k+1 issues BEFORE the 96-MFMA cluster on tile k
// so HBM/L3 latency hides under compute. Epilogue: +bias, softplus on
// delta columns [DM, 2*DM).
#define BM 256
#define BN 256
#define BK 32
#define KT (KDIM / BK)       // 32

template <typename OutT>
__global__ __launch_bounds__(512, 2)
void gemm_kernel(const u16* __restrict__ xHi, const u16* __restrict__ xLo,
                 const u16* __restrict__ wHi, const u16* __restrict__ wLo,
                 const float* __restrict__ bias, OutT* __restrict__ xp) {
  // 4 x 32KB = 128 KB
  __shared__ __align__(16) u16 sA0[16384];
  __shared__ __align__(16) u16 sB0[16384];
  __shared__ __align__(16) u16 sA1[16384];
  __shared__ __align__(16) u16 sB1[16384];

  const int tid  = threadIdx.x;
  const int lane = tid & 63;
  const int wid  = tid >> 6;       // 0..7
  const int wr   = wid >> 2;       // wave row (0..1), 128 rows each
  const int wc   = wid & 3;        // wave col (0..3), 64 cols each
  const int fr   = lane & 15;

  // XCD-aware bijective swizzle: 2176 = 8 * 272. Each XCD gets 272
  // consecutive wgids = 17 n-tiles x 16 m-tiles (m-major inside n-tile).
  const int bid = blockIdx.x;
  const int wg  = (bid & 7) * 272 + (bid >> 3);
  const int mt  = wg & 15;
  const int nt  = wg >> 4;
  const int m0  = mt * BM;
  const int n0  = nt * BN;

  // ---- staging source pointers (inverse-swizzled) ----
  // LDS linear byte p = tid*16 + j*8192 ; logical q = p ^ (((p>>7)&7)<<4)
  // q -> row = q>>7, half = (q>>6)&1 (0=hi,1=lo), koff = q&63 bytes.
  const u16* srcA[4];
  const u16* srcB[4];
#pragma unroll
  for (int j = 0; j < 4; ++j) {
    const u32 p = (u32)tid * 16u + (u32)j * 8192u;
    const u32 q = p ^ (((p >> 7) & 7u) << 4);
    const int row  = (int)(q >> 7);
    const int half = (int)((q >> 6) & 1u);
    const int koff = (int)(q & 63u) >> 1;   // u16 elements
    srcA[j] = (half ? xLo : xHi) + (size_t)(m0 + row) * KDIM + koff;
    srcB[j] = (half ? wLo : wHi) + (size_t)(n0 + row) * KDIM + koff;
  }

  // ---- compute-side swizzled LDS byte offsets ----
  const int inner = (((lane >> 4) * 16) ^ ((lane & 7) << 4));
  int aOff[8], bOff[4];
#pragma unroll
  for (int mi = 0; mi < 8; ++mi)
    aOff[mi] = (wr * 128 + mi * 16 + fr) * 128 + inner;
#pragma unroll
  for (int nj = 0; nj < 4; ++nj)
    bOff[nj] = (wc * 64 + nj * 16 + fr) * 128 + inner;

  f32x4 acc[8][4] = {};

  auto stage = [&](u16* sAn, u16* sBn) {
#pragma unroll
    for (int j = 0; j < 4; ++j) {
      gl16(srcA[j], (char*)sAn + tid * 16 + j * 8192);
      srcA[j] += BK;
    }
#pragma unroll
    for (int j = 0; j < 4; ++j) {
      gl16(srcB[j], (char*)sBn + tid * 16 + j * 8192);
      srcB[j] += BK;
    }
  };

  auto step = [&](const u16* sAc, const u16* sBc, u16* sAn, u16* sBn,
                  bool doStage) {
    if (doStage) stage(sAn, sBn);          // next tile's loads fly under MFMA
    const char* cA = (const char*)sAc;
    const char* cB = (const char*)sBc;
    bf16x8 bh[4], bl[4];
#pragma unroll
    for (int nj = 0; nj < 4; ++nj) {
      bh[nj] = *(const bf16x8*)(cB + bOff[nj]);
      bl[nj] = *(const bf16x8*)(cB + (bOff[nj] ^ 64));
    }
    __builtin_amdgcn_s_setprio(1);
#pragma unroll
    for (int mi = 0; mi < 8; ++mi) {
      bf16x8 ah = *(const bf16x8*)(cA + aOff[mi]);
      bf16x8 al = *(const bf16x8*)(cA + (aOff[mi] ^ 64));
#pragma unroll
      for (int nj = 0; nj < 4; ++nj) {
        acc[mi][nj] = mfma16(ah, bh[nj], acc[mi][nj]);
        acc[mi][nj] = mfma16(ah, bl[nj], acc[mi][nj]);
        acc[mi][nj] = mfma16(al, bh[nj], acc[mi][nj]);
      }
    }
    __builtin_amdgcn_s_setprio(0);
    // FULL drain before raw barrier: vmcnt for our stage writes, lgkmcnt so
    // no ds_read of the cur buffer is still in flight when the next step's
    // global_load_lds overwrites it (__syncthreads-equivalent semantics).
    asm volatile("s_waitcnt vmcnt(0) lgkmcnt(0)" ::: "memory");
    __builtin_amdgcn_s_barrier();
  };

  // prologue: stage tile 0
  stage(sA0, sB0);
  asm volatile("s_waitcnt vmcnt(0) lgkmcnt(0)" ::: "memory");
  __builtin_amdgcn_s_barrier();

#pragma unroll 1
  for (int t = 0; t < KT / 2; ++t) {
    step(sA0, sB0, sA1, sB1, true);
    step(sA1, sB1, sA0, sB0, t < KT / 2 - 1);
  }

  // epilogue: C/D layout col = lane&15 (n), row = (lane>>4)*4 + j (m)
  const int rq = (lane >> 4) * 4;
#pragma unroll
  for (int mi = 0; mi < 8; ++mi) {
#pragma unroll
    for (int nj = 0; nj < 4; ++nj) {
      const int col = n0 + wc * 64 + nj * 16 + fr;
      const float bv = bias[col];
      const bool isdelta = (col >= DM) && (col < 2 * DM);
      const int row = m0 + wr * 128 + mi * 16 + rq;
#pragma unroll
      for (int j = 0; j < 4; ++j) {
        float v = acc[mi][nj][j] + bv;
        if (isdelta) v = (v > 20.f) ? v : log1pf(__expf(v));
        stf(&xp[(size_t)(row + j) * PROJ + col], v);
      }
    }
  }
}

// ---------------- scan phase 1: per-chunk (prod a, local h) ----------------
// block = 256 threads = 16 d x 16 n; grid = BATCH * 64 d-tiles * NCHUNK
template <typename InT>
__global__ __launch_bounds__(256)
void scan_phase1(const InT* __restrict__ xp, const float* __restrict__ A,
                 float* __restrict__ P, float* __restrict__ Hl) {
  const int bidx = blockIdx.x;
  const int c  = bidx & 15;
  const int dt = (bidx >> 4) & 63;
  const int b  = bidx >> 10;
  const int tid = threadIdx.x;
  const int n  = tid & 15;
  const int dl = tid >> 4;
  const int d  = dt * 16 + dl;

  const float Ad = A[d * DS + n];
  const size_t row0 = ((size_t)(b * SEQ) + c * CHUNK) * PROJ;
  const InT* pu = xp + row0 + d;
  const InT* pq = xp + row0 + DM + d;              // softplus(delta), from epilogue
  const InT* pB = xp + row0 + 2 * DM + d * DS + n;

  float p = 1.f, h = 0.f;
  for (int t = 0; t < CHUNK; ++t) {
    float u  = ldf(pu);
    float dq = ldf(pq);
    float Bv = ldf(pB);
    float a  = __expf(Ad * dq);
    h = a * h + Bv * u;
    p *= a;
    pu += PROJ; pq += PROJ; pB += PROJ;
  }
  const int ch = ((b * DM + d) * DS + n);
  P[(size_t)c * NCH + ch]  = p;
  Hl[(size_t)c * NCH + ch] = h;
}

// ---------------- scan phase 2: prefix over chunks ----------------
__global__ __launch_bounds__(256)
void scan_phase2(const float* __restrict__ P, const float* __restrict__ Hl,
                 float* __restrict__ Hst) {
  const int ch = blockIdx.x * 256 + threadIdx.x;
  float h = 0.f;
  for (int c = 0; c < NCHUNK; ++c) {
    Hst[(size_t)c * NCH + ch] = h;
    h = P[(size_t)c * NCH + ch] * h + Hl[(size_t)c * NCH + ch];
  }
}

// ---------------- scan phase 3: replay with start state, emit y ------------
template <typename InT>
__global__ __launch_bounds__(256)
void scan_phase3(const InT* __restrict__ xp, const float* __restrict__ A,
                 const float* __restrict__ Dv, const float* __restrict__ Hst,
                 float* __restrict__ y) {
  const int bidx = blockIdx.x;
  const int c  = bidx & 15;
  const int dt = (bidx >> 4) & 63;
  const int b  = bidx >> 10;
  const int tid = threadIdx.x;
  const int n  = tid & 15;
  const int dl = tid >> 4;
  const int d  = dt * 16 + dl;

  const float Ad = A[d * DS + n];
  const float Dd = Dv[d];
  const int ch = ((b * DM + d) * DS + n);
  float h = Hst[(size_t)c * NCH + ch];

  const int t0 = c * CHUNK;
  const size_t row0 = ((size_t)(b * SEQ) + t0) * PROJ;
  const InT* pu = xp + row0 + d;
  const InT* pq = xp + row0 + DM + d;
  const InT* pB = xp + row0 + 2 * DM + d * DS + n;
  const InT* pC = pB + DM * DS;
  float* py = y + ((size_t)(b * SEQ) + t0) * DM + d;

  for (int t = 0; t < CHUNK; ++t) {
    float u  = ldf(pu);
    float dq = ldf(pq);
    float Bv = ldf(pB);
    float Cv = ldf(pC);
    float a  = __expf(Ad * dq);
    h = a * h + Bv * u;
    float ph = Cv * h;
    ph += __shfl_xor(ph, 1);
    ph += __shfl_xor(ph, 2);
    ph += __shfl_xor(ph, 4);
    ph += __shfl_xor(ph, 8);
    if (n == 0) *py = ph + Dd * u;
    pu += PROJ; pq += PROJ; pB += PROJ; pC += PROJ; py += DM;
  }
}

// ---------------- launch ----------------
extern "C" void kernel_launch(void* const* d_in, const int* in_sizes, int n_in,
                              void* d_out, int out_size, void* d_ws, size_t ws_size,
                              hipStream_t stream) {
  const float* x  = (const float*)d_in[0];
  const float* W  = (const float*)d_in[1];
  const float* b  = (const float*)d_in[2];
  const float* A  = (const float*)d_in[3];
  const float* Dv = (const float*)d_in[4];
  float* y = (float*)d_out;

  char* ws = (char*)d_ws;
  size_t off = 0;
  auto alloc = [&](size_t bytes) {
    void* p = ws + off;
    off += (bytes + 255) & ~(size_t)255;
    return p;
  };

  u16* xHi = (u16*)alloc((size_t)MTOK * KDIM * sizeof(u16));
  u16* xLo = (u16*)alloc((size_t)MTOK * KDIM * sizeof(u16));
  u16* wHi = (u16*)alloc((size_t)PROJ * KDIM * sizeof(u16));
  u16* wLo = (u16*)alloc((size_t)PROJ * KDIM * sizeof(u16));
  float* P   = (float*)alloc((size_t)NCHUNK * NCH * sizeof(float));
  float* Hl  = (float*)alloc((size_t)NCHUNK * NCH * sizeof(float));
  float* Hst = (float*)alloc((size_t)NCHUNK * NCH * sizeof(float));
  // xp last so its size can flex on available workspace.
  // NOTE: no unsigned subtraction — ws_size may be smaller than off.
  const size_t xp_elems = (size_t)MTOK * PROJ;
  const bool xp_f32 = ws_size >= off + xp_elems * sizeof(float);
  void* xp = alloc(xp_elems * (xp_f32 ? sizeof(float) : sizeof(__hip_bfloat16)));

  // split x and W into bf16 hi/lo
  split_kernel<<<(MTOK * KDIM / 4 + 255) / 256, 256, 0, stream>>>(x, xHi, xLo, MTOK * KDIM / 4);
  split_kernel<<<(PROJ * KDIM / 4 + 255) / 256, 256, 0, stream>>>(W, wHi, wLo, PROJ * KDIM / 4);

  const int gemm_grid = (MTOK / BM) * (PROJ / BN);   // 16 * 136 = 2176
  const int scan_grid = BATCH * 64 * NCHUNK;

  if (xp_f32) {
    float* xpf = (float*)xp;
    gemm_kernel<float><<<gemm_grid, 512, 0, stream>>>(xHi, xLo, wHi, wLo, b, xpf);
    scan_phase1<float><<<scan_grid, 256, 0, stream>>>(xpf, A, P, Hl);
    scan_phase2<<<NCH / 256, 256, 0, stream>>>(P, Hl, Hst);
    scan_phase3<float><<<scan_grid, 256, 0, stream>>>(xpf, A, Dv, Hst, y);
  } else {
    __hip_bfloat16* xpb = (__hip_bfloat16*)xp;
    gemm_kernel<__hip_bfloat16><<<gemm_grid, 512, 0, stream>>>(xHi, xLo, wHi, wLo, b, xpb);
    scan_phase1<__hip_bfloat16><<<scan_grid, 256, 0, stream>>>(xpb, A, P, Hl);
    scan_phase2<<<NCH / 256, 256, 0, stream>>>(P, Hl, Hst);
    scan_phase3<__hip_bfloat16><<<scan_grid, 256, 0, stream>>>(xpb, A, Dv, Hst, y);
  }
}